// Round 4
// baseline (130.745 us; speedup 1.0000x reference)
//
#include <hip/hip_runtime.h>
#include <hip/hip_bf16.h>
#include <math.h>

// KoLeo loss, MI355X. Fused normalize -> bf16 fragment repack -> MFMA gram
// row-max (never materializes the 16384^2 gram) -> log/mean epilogue.
//
// v4: j-tile pairs per iteration -> 4 independent MFMA chains per wave
// (covers dependent-MFMA latency at 2 waves/SIMD) + half the barriers.
//
// F layout (32-row tiles): chunk(t32,ks,lane) = t32*1024 + ks*64 + lane,
//   16B chunk = 8 bf16 of xn[t32*32 + (lane&31)][ks*16 + (lane>>5)*8 .. +7].
// This IS the mfma_f32_32x32x16_bf16 A/B fragment layout, so operand loads /
// LDS staging are fully-coalesced linear 16B-per-lane transfers.

typedef __attribute__((ext_vector_type(8))) short bf16x8;    // 8 bf16 = 4 VGPR
typedef __attribute__((ext_vector_type(16))) float f32x16;   // 32x32 acc

#define NROWS 16384
#define NDIM  256
#define JSPLIT 8
#define JT32_PER (NROWS / 32 / JSPLIT)   // 64 j-tiles (32 rows) per block
#define NPAIR   (JT32_PER / 2)           // 32 tile-pairs

// ---------------- K0: row 1/norm ----------------
__global__ __launch_bounds__(256) void knorm(const float* __restrict__ x,
                                             float* __restrict__ rn) {
    int wid = threadIdx.x >> 6, lane = threadIdx.x & 63;
    int row = blockIdx.x * 4 + wid;                 // 4096 blocks * 4 waves
    const float4* xr = (const float4*)(x + (size_t)row * NDIM);
    float4 v = xr[lane];                            // 64 lanes * 4 f32 = 256
    float ss = v.x * v.x + v.y * v.y + v.z * v.z + v.w * v.w;
    #pragma unroll
    for (int m = 1; m < 64; m <<= 1) ss += __shfl_xor(ss, m, 64);
    if (lane == 0) rn[row] = 1.0f / fmaxf(sqrtf(ss), 1e-12f);
}

// ---------------- K1: normalize + pack to 32x32 fragment layout -----------
__device__ inline unsigned bf_rne(float f) {
    union { float f; unsigned u; } c; c.f = f;
    return (c.u + 0x7FFFu + ((c.u >> 16) & 1u)) >> 16;
}
__device__ inline unsigned pack2(float lo, float hi) {
    return bf_rne(lo) | (bf_rne(hi) << 16);
}

__global__ __launch_bounds__(256) void kpack(const float* __restrict__ x,
                                             const float* __restrict__ rn,
                                             uint4* __restrict__ F) {
    int g = blockIdx.x * 256 + threadIdx.x;         // chunk id, 524288 total
    int t32  = g >> 10;                             // 1024 chunks per 32-row tile
    int rem  = g & 1023;
    int ks   = rem >> 6;                            // 16 k-steps of 16
    int lane = rem & 63;
    int row  = t32 * 32 + (lane & 31);
    int kb   = ks * 16 + (lane >> 5) * 8;
    float s = rn[row];
    const float4* xr = (const float4*)(x + (size_t)row * NDIM + kb);
    float4 a = xr[0], b = xr[1];
    uint4 o;
    o.x = pack2(a.x * s, a.y * s);
    o.y = pack2(a.z * s, a.w * s);
    o.z = pack2(b.x * s, b.y * s);
    o.w = pack2(b.z * s, b.w * s);
    F[g] = o;                                       // fully coalesced 16B
}

// ---------------- K2: fused gram + row-max (LDS-shared j-stream) ----------
__device__ inline void stage16(const uint4* __restrict__ g, const uint4* l) {
    __builtin_amdgcn_global_load_lds(
        (const __attribute__((address_space(1))) unsigned*)g,
        (__attribute__((address_space(3))) unsigned*)l, 16, 0, 0);
}

// 256 blocks (32 i-blocks x 8 j-slices), 512 threads = 8 waves.
// Wave holds 2 x 32-row i-tiles in regs (128 VGPR), streams PAIRS of 32-row
// j-tiles through double-buffered LDS (2 x 32KB); 64 MFMA per pair per wave
// across 4 independent accumulator chains.
__global__ __launch_bounds__(512, 2) void kmax(const uint4* __restrict__ F,
                                               float* __restrict__ part) {
    __shared__ uint4 sbuf[2][2048];                 // 2 x 32KB j-tile-pair bufs

    const int tid  = threadIdx.x;
    const int wid  = tid >> 6;
    const int lane = tid & 63;
    const int ib   = blockIdx.x >> 3;               // i-block (512 rows)
    const int js   = blockIdx.x & 7;                // j-slice (XCD-aligned)
    const int i0w  = ib * 512 + wid * 64;           // wave's first i-row
    const int itb  = ib * 16 + wid * 2;             // wave's first 32-row i-tile

    // hoist i-side fragments: 2 tiles x 16 ksteps x 4 VGPR = 128 VGPR
    bf16x8 bfr0[16], bfr1[16];
    #pragma unroll
    for (int ks = 0; ks < 16; ++ks) {
        bfr0[ks] = ((const bf16x8*)F)[(itb + 0) * 1024 + ks * 64 + lane];
        bfr1[ks] = ((const bf16x8*)F)[(itb + 1) * 1024 + ks * 64 + lane];
    }

    const int jt0 = js * JT32_PER;                  // global first j-tile
    // prologue: stage pair 0 (2048 chunks, 4 x 16B per thread) into buf 0
    {
        const uint4* gp = F + (size_t)jt0 * 1024;
        #pragma unroll
        for (int s = 0; s < 4; ++s)
            stage16(gp + s * 512 + tid, &sbuf[0][s * 512 + wid * 64]);
    }
    __syncthreads();

    float rmax0 = -1e30f, rmax1 = -1e30f;
    // diagonal: i_local = lane&31 (col); j_local = (r&3)+8*(r>>2)+4*(lane>>5)
    const int L  = lane & 31, hi = lane >> 5;
    const bool dvalid = (((L >> 2) & 1) == hi);
    const int  dreg   = (L & 3) | ((L >> 3) << 2);

    int cur = 0;
    for (int p = 0; p < NPAIR; ++p) {
        if (p + 1 < NPAIR) {                        // stage next pair
            const uint4* gp = F + (size_t)(jt0 + 2 * (p + 1)) * 1024;
            #pragma unroll
            for (int s = 0; s < 4; ++s)
                stage16(gp + s * 512 + tid, &sbuf[cur ^ 1][s * 512 + wid * 64]);
        }

        // 4 independent accumulator chains: c{jsub}{itile}
        f32x16 c00 = {0.f}, c01 = {0.f}, c10 = {0.f}, c11 = {0.f};
        #pragma unroll
        for (int ks = 0; ks < 16; ++ks) {
            bf16x8 af0 = *(const bf16x8*)&sbuf[cur][ks * 64 + lane];
            bf16x8 af1 = *(const bf16x8*)&sbuf[cur][1024 + ks * 64 + lane];
            c00 = __builtin_amdgcn_mfma_f32_32x32x16_bf16(af0, bfr0[ks], c00, 0, 0, 0);
            c01 = __builtin_amdgcn_mfma_f32_32x32x16_bf16(af0, bfr1[ks], c01, 0, 0, 0);
            c10 = __builtin_amdgcn_mfma_f32_32x32x16_bf16(af1, bfr0[ks], c10, 0, 0, 0);
            c11 = __builtin_amdgcn_mfma_f32_32x32x16_bf16(af1, bfr1[ks], c11, 0, 0, 0);
        }

        unsigned dd0 = (unsigned)((jt0 + 2 * p) * 32 - i0w);   // j-sub-tile 0
        unsigned dd1 = dd0 + 32;                               // j-sub-tile 1
        if (dd0 < 64u || dd1 < 64u) {               // wave-uniform branch
            #pragma unroll
            for (int r = 0; r < 16; ++r) {
                float v00 = c00[r], v01 = c01[r], v10 = c10[r], v11 = c11[r];
                bool dr = dvalid && (r == dreg);
                if (dr && dd0 < 64u) { if ((dd0 >> 5) == 0) v00 = -1e30f; else v01 = -1e30f; }
                if (dr && dd1 < 64u) { if ((dd1 >> 5) == 0) v10 = -1e30f; else v11 = -1e30f; }
                rmax0 = fmaxf(rmax0, fmaxf(v00, v10));
                rmax1 = fmaxf(rmax1, fmaxf(v01, v11));
            }
        } else {
            #pragma unroll
            for (int r = 0; r < 16; ++r) {
                rmax0 = fmaxf(rmax0, fmaxf(c00[r], c10[r]));
                rmax1 = fmaxf(rmax1, fmaxf(c01[r], c11[r]));
            }
        }

        __syncthreads();                            // drains stage vmcnt too
        cur ^= 1;
    }

    // lanes l and l^32 share the same i-col; combine then write from lane<32
    rmax0 = fmaxf(rmax0, __shfl_xor(rmax0, 32, 64));
    rmax1 = fmaxf(rmax1, __shfl_xor(rmax1, 32, 64));
    if (lane < 32) {
        part[(size_t)js * NROWS + i0w + L]      = rmax0;
        part[(size_t)js * NROWS + i0w + 32 + L] = rmax1;
    }
}

// ---------------- K3: loss epilogue (combine j-slice partials) ------------
__global__ __launch_bounds__(1024) void kloss(const float* __restrict__ part,
                                              float* __restrict__ out) {
    float acc = 0.f;
    for (int i = threadIdx.x; i < NROWS; i += 1024) {
        float g = part[i];
        #pragma unroll
        for (int p = 1; p < JSPLIT; ++p) g = fmaxf(g, part[p * NROWS + i]);
        float d = sqrtf(fmaxf(2.f - 2.f * g, 0.f));
        acc += logf(d + 1e-8f);
    }
    #pragma unroll
    for (int m = 1; m < 64; m <<= 1) acc += __shfl_xor(acc, m, 64);
    __shared__ float p[16];
    int wid = threadIdx.x >> 6, lane = threadIdx.x & 63;
    if (lane == 0) p[wid] = acc;
    __syncthreads();
    if (threadIdx.x == 0) {
        float s = 0.f;
        #pragma unroll
        for (int w = 0; w < 16; ++w) s += p[w];
        out[0] = -s / (float)NROWS;
    }
}

extern "C" void kernel_launch(void* const* d_in, const int* in_sizes, int n_in,
                              void* d_out, int out_size, void* d_ws, size_t ws_size,
                              hipStream_t stream) {
    const float* x = (const float*)d_in[0];
    float* out = (float*)d_out;
    char* ws = (char*)d_ws;

    uint4* F     = (uint4*)ws;                                  // 8 MiB
    float* rn    = (float*)(ws + 8u * 1024u * 1024u);           // 64 KiB
    float* part  = (float*)(ws + 8u * 1024u * 1024u + 65536u);  // 512 KiB

    knorm<<<NROWS / 4, 256, 0, stream>>>(x, rn);
    kpack<<<(NROWS * NDIM / 8) / 256, 256, 0, stream>>>(x, rn, F);
    kmax <<<(NROWS / 512) * JSPLIT, 512, 0, stream>>>(F, part);
    kloss<<<1, 1024, 0, stream>>>(part, out);
}

// Round 5
// 111.923 us; speedup vs baseline: 1.1682x; 1.1682x over previous
//
#include <hip/hip_runtime.h>
#include <hip/hip_bf16.h>
#include <math.h>

// KoLeo loss, MI355X. Fused normalize -> bf16 fragment repack -> MFMA gram
// row-max (never materializes the 16384^2 gram) -> log/mean epilogue.
//
// v5: SYMMETRIC halving. G = Xn Xn^T is symmetric, so only super-diagonal
// 512x64 tile units are computed (4224 of 8192). Each unit yields
//   - i-side row-max (per-lane over acc regs, as before)
//   - j-side col-max (DPP row_ror reduce over 16-lane groups, VALU-only)
// Partials combine through atomicMax on monotone uint keys in rowcand[].
// 256 blocks snake a flattened triangular unit list (16/17 units each),
// reloading i-fragments (128 VGPR) at rare ib transitions.
//
// F layout (32-row tiles): chunk(t32,ks,lane) = t32*1024 + ks*64 + lane,
//   16B chunk = 8 bf16 of xn[t32*32 + (lane&31)][ks*16 + (lane>>5)*8 .. +7].
// == mfma_f32_32x32x16_bf16 A/B fragment layout -> linear coalesced staging.

typedef __attribute__((ext_vector_type(8))) short bf16x8;    // 8 bf16 = 4 VGPR
typedef __attribute__((ext_vector_type(16))) float f32x16;   // 32x32 acc

#define NROWS 16384
#define NDIM  256
#define NBLK  256
#define NUNITS 4224   // sum over ib<32 of (256-8*ib)

// ---------------- K0: row 1/norm ----------------
__global__ __launch_bounds__(256) void knorm(const float* __restrict__ x,
                                             float* __restrict__ rn) {
    int wid = threadIdx.x >> 6, lane = threadIdx.x & 63;
    int row = blockIdx.x * 4 + wid;
    const float4* xr = (const float4*)(x + (size_t)row * NDIM);
    float4 v = xr[lane];
    float ss = v.x * v.x + v.y * v.y + v.z * v.z + v.w * v.w;
    #pragma unroll
    for (int m = 1; m < 64; m <<= 1) ss += __shfl_xor(ss, m, 64);
    if (lane == 0) rn[row] = 1.0f / fmaxf(sqrtf(ss), 1e-12f);
}

// ---------------- K1: normalize + pack to 32x32 fragment layout -----------
__device__ inline unsigned bf_rne(float f) {
    union { float f; unsigned u; } c; c.f = f;
    return (c.u + 0x7FFFu + ((c.u >> 16) & 1u)) >> 16;
}
__device__ inline unsigned pack2(float lo, float hi) {
    return bf_rne(lo) | (bf_rne(hi) << 16);
}

__global__ __launch_bounds__(256) void kpack(const float* __restrict__ x,
                                             const float* __restrict__ rn,
                                             uint4* __restrict__ F) {
    int g = blockIdx.x * 256 + threadIdx.x;
    int t32  = g >> 10;
    int rem  = g & 1023;
    int ks   = rem >> 6;
    int lane = rem & 63;
    int row  = t32 * 32 + (lane & 31);
    int kb   = ks * 16 + (lane >> 5) * 8;
    float s = rn[row];
    const float4* xr = (const float4*)(x + (size_t)row * NDIM + kb);
    float4 a = xr[0], b = xr[1];
    uint4 o;
    o.x = pack2(a.x * s, a.y * s);
    o.y = pack2(a.z * s, a.w * s);
    o.z = pack2(b.x * s, b.y * s);
    o.w = pack2(b.z * s, b.w * s);
    F[g] = o;
}

// ---------------- helpers ----------------
__device__ inline void stage16(const uint4* __restrict__ g, const uint4* l) {
    __builtin_amdgcn_global_load_lds(
        (const __attribute__((address_space(1))) unsigned*)g,
        (__attribute__((address_space(3))) unsigned*)l, 16, 0, 0);
}

// monotone float->uint key (order-preserving); inverse in kloss
__device__ inline unsigned fkey(float f) {
    unsigned u = __builtin_bit_cast(unsigned, f);
    return (u & 0x80000000u) ? ~u : (u | 0x80000000u);
}

template<int CTRL>
__device__ inline float dpp_max(float x) {
    int xi = __builtin_bit_cast(int, x);
    int yi = __builtin_amdgcn_update_dpp(xi, xi, CTRL, 0xF, 0xF, false);
    return fmaxf(x, __builtin_bit_cast(float, yi));
}
// max over each 16-lane row (row_ror 1,2,4,8) -> every lane holds row max
__device__ inline float rowmax16(float x) {
    x = dpp_max<0x121>(x);   // row_ror:1
    x = dpp_max<0x122>(x);   // row_ror:2
    x = dpp_max<0x124>(x);   // row_ror:4
    x = dpp_max<0x128>(x);   // row_ror:8
    return x;
}

// ---------------- K2: symmetric fused gram + two-sided max ----------------
// 256 blocks x 512 threads (8 waves, 2/SIMD). Unit = 512 i-rows x 64 j-rows.
__global__ __launch_bounds__(512, 2) void kmax(const uint4* __restrict__ F,
                                               unsigned* __restrict__ rowcand) {
    __shared__ uint4 sbuf[2][2048];                 // 2 x 32KB j-pair buffers
    __shared__ unsigned jl[2][64];                  // per-unit j-max combine

    const int tid  = threadIdx.x;
    const int wid  = tid >> 6;
    const int lane = tid & 63;
    const int L    = lane & 31;
    const int hi   = lane >> 5;

    if (tid < 128) ((unsigned*)jl)[tid] = 0u;

    // snake assignment: block b handles units [b*16.5, (b+1)*16.5)
    const int b = blockIdx.x;
    const int u0   = (b * 33) >> 1;
    const int uend = ((b + 1) * 33) >> 1;

    // unit u -> (ib, uj): prefix T(ib) = 4*ib*(65-ib), row len 256-8*ib
    int cib = 0;
    while (4 * (cib + 1) * (64 - cib) <= u0) ++cib;
    int cuj = u0 - 4 * cib * (65 - cib);

    // i-side fragments for cib: 2 x 32-row tiles x 16 ks = 128 VGPR
    bf16x8 bfr0[16], bfr1[16];
    {
        int itb = cib * 16 + wid * 2;
        #pragma unroll
        for (int ks = 0; ks < 16; ++ks) {
            bfr0[ks] = ((const bf16x8*)F)[(itb + 0) * 1024 + ks * 64 + lane];
            bfr1[ks] = ((const bf16x8*)F)[(itb + 1) * 1024 + ks * 64 + lane];
        }
    }

    // prologue: stage unit u0 into buf 0
    {
        const uint4* gp = F + (size_t)(cib * 16 + cuj * 2) * 1024;
        #pragma unroll
        for (int s = 0; s < 4; ++s)
            stage16(gp + s * 512 + tid, &sbuf[0][s * 512 + wid * 64]);
    }
    __syncthreads();

    float rmax0 = -1e30f, rmax1 = -1e30f;
    // diagonal position in 32x32 C: col=lane&31 -> i; row=(r&3)+8(r>>2)+4hi -> j
    const bool dvalid = (((L >> 2) & 1) == hi);
    const int  dreg   = (L & 3) | ((L >> 3) << 2);
    const int  idx    = lane & 15;
    const int  jrbase = (idx & 3) + 8 * (idx >> 2) + 4 * hi;  // writer j-row

    int cur = 0;
    for (int s = u0; s < uend; ++s) {
        // next unit in the triangular walk
        int nib = cib, nuj = cuj + 1;
        if (nuj == 256 - 8 * cib) { nib = cib + 1; nuj = 0; }

        if (s + 1 < uend) {                         // stage next unit
            const uint4* gp = F + (size_t)(nib * 16 + nuj * 2) * 1024;
            #pragma unroll
            for (int t = 0; t < 4; ++t)
                stage16(gp + t * 512 + tid, &sbuf[cur ^ 1][t * 512 + wid * 64]);
        }

        // ---- MFMA phase: 4 chains c{jsub}{itile} ----
        f32x16 c00 = {0.f}, c01 = {0.f}, c10 = {0.f}, c11 = {0.f};
        #pragma unroll
        for (int ks = 0; ks < 16; ++ks) {
            bf16x8 af0 = *(const bf16x8*)&sbuf[cur][ks * 64 + lane];
            bf16x8 af1 = *(const bf16x8*)&sbuf[cur][1024 + ks * 64 + lane];
            c00 = __builtin_amdgcn_mfma_f32_32x32x16_bf16(af0, bfr0[ks], c00, 0, 0, 0);
            c01 = __builtin_amdgcn_mfma_f32_32x32x16_bf16(af0, bfr1[ks], c01, 0, 0, 0);
            c10 = __builtin_amdgcn_mfma_f32_32x32x16_bf16(af1, bfr0[ks], c10, 0, 0, 0);
            c11 = __builtin_amdgcn_mfma_f32_32x32x16_bf16(af1, bfr1[ks], c11, 0, 0, 0);
        }

        // ---- masks + both-sided max ----
        // diag unit iff unit's j-pair == wave's i-rows: uj == wid
        const bool dg = (cuj == wid);
        float jm0[16], jm1[16];
        #pragma unroll
        for (int r = 0; r < 16; ++r) {
            float v00 = c00[r], v01 = c01[r], v10 = c10[r], v11 = c11[r];
            if (dg && dvalid && r == dreg) { v00 = -1e30f; v11 = -1e30f; }
            rmax0 = fmaxf(rmax0, fmaxf(v00, v10));
            rmax1 = fmaxf(rmax1, fmaxf(v01, v11));
            jm0[r] = fmaxf(v00, v01);               // jsub0: max over itiles
            jm1[r] = fmaxf(v10, v11);               // jsub1
        }
        // DPP reduce over 16-lane i-groups, then lane idx picks reg idx
        #pragma unroll
        for (int r = 0; r < 16; ++r) { jm0[r] = rowmax16(jm0[r]);
                                       jm1[r] = rowmax16(jm1[r]); }
        float wv0 = jm0[0], wv1 = jm1[0];
        #pragma unroll
        for (int r = 1; r < 16; ++r) {
            wv0 = (idx == r) ? jm0[r] : wv0;
            wv1 = (idx == r) ? jm1[r] : wv1;
        }
        atomicMax(&jl[cur][jrbase],      fkey(wv0));
        atomicMax(&jl[cur][32 + jrbase], fkey(wv1));

        __syncthreads();                            // buffers + jl ready

        // flush jl[cur] -> rowcand (one wavefront's worth of lanes)
        if (tid < 64) {
            unsigned k = jl[cur][tid];
            atomicMax(&rowcand[cib * 512 + cuj * 64 + tid], k);
            jl[cur][tid] = 0u;                      // reused at s+2 (safe)
        }

        if (s + 1 < uend && nib != cib) {           // ib transition
            // flush i-side running max for cib
            float f0 = fmaxf(rmax0, __shfl_xor(rmax0, 32, 64));
            float f1 = fmaxf(rmax1, __shfl_xor(rmax1, 32, 64));
            if (lane < 32) {
                int i0w = cib * 512 + wid * 64;
                atomicMax(&rowcand[i0w + L],      fkey(f0));
                atomicMax(&rowcand[i0w + 32 + L], fkey(f1));
            }
            rmax0 = rmax1 = -1e30f;
            int itb = nib * 16 + wid * 2;           // reload i-fragments
            #pragma unroll
            for (int ks = 0; ks < 16; ++ks) {
                bfr0[ks] = ((const bf16x8*)F)[(itb + 0) * 1024 + ks * 64 + lane];
                bfr1[ks] = ((const bf16x8*)F)[(itb + 1) * 1024 + ks * 64 + lane];
            }
        }
        cib = nib; cuj = nuj; cur ^= 1;
    }

    // final i-side flush (cib may have advanced past last processed row only
    // when a transition already flushed; flushing -1e30 keys is harmless,
    // but guard OOB when cib == 32)
    if (cib < 32) {
        float f0 = fmaxf(rmax0, __shfl_xor(rmax0, 32, 64));
        float f1 = fmaxf(rmax1, __shfl_xor(rmax1, 32, 64));
        if (lane < 32) {
            int i0w = cib * 512 + wid * 64;
            atomicMax(&rowcand[i0w + L],      fkey(f0));
            atomicMax(&rowcand[i0w + 32 + L], fkey(f1));
        }
    }
}

// ---------------- K3: loss epilogue (decode keys) ----------------
__global__ __launch_bounds__(1024) void kloss(const unsigned* __restrict__ rowcand,
                                              float* __restrict__ out) {
    float acc = 0.f;
    for (int i = threadIdx.x; i < NROWS; i += 1024) {
        unsigned k = rowcand[i];
        unsigned u = (k & 0x80000000u) ? (k ^ 0x80000000u) : ~k;
        float g = __builtin_bit_cast(float, u);
        float d = sqrtf(fmaxf(2.f - 2.f * g, 0.f));
        acc += logf(d + 1e-8f);
    }
    #pragma unroll
    for (int m = 1; m < 64; m <<= 1) acc += __shfl_xor(acc, m, 64);
    __shared__ float p[16];
    int wid = threadIdx.x >> 6, lane = threadIdx.x & 63;
    if (lane == 0) p[wid] = acc;
    __syncthreads();
    if (threadIdx.x == 0) {
        float s = 0.f;
        #pragma unroll
        for (int w = 0; w < 16; ++w) s += p[w];
        out[0] = -s / (float)NROWS;
    }
}

extern "C" void kernel_launch(void* const* d_in, const int* in_sizes, int n_in,
                              void* d_out, int out_size, void* d_ws, size_t ws_size,
                              hipStream_t stream) {
    const float* x = (const float*)d_in[0];
    float* out = (float*)d_out;
    char* ws = (char*)d_ws;

    uint4*    F       = (uint4*)ws;                                 // 8 MiB
    float*    rn      = (float*)(ws + 8u * 1024u * 1024u);          // 64 KiB
    unsigned* rowcand = (unsigned*)(ws + 8u * 1024u * 1024u + 65536u); // 64 KiB

    hipMemsetAsync(rowcand, 0, NROWS * sizeof(unsigned), stream);
    knorm<<<NROWS / 4, 256, 0, stream>>>(x, rn);
    kpack<<<(NROWS * NDIM / 8) / 256, 256, 0, stream>>>(x, rn, F);
    kmax <<<NBLK, 512, 0, stream>>>(F, rowcand);
    kloss<<<1, 1024, 0, stream>>>(rowcand, out);
}